// Round 2
// baseline (803.333 us; speedup 1.0000x reference)
//
#include <hip/hip_runtime.h>
#include <math.h>

// ---------- types ----------
typedef __bf16 bf16x8 __attribute__((ext_vector_type(8)));
typedef float f32x4 __attribute__((ext_vector_type(4)));
typedef unsigned short us4v __attribute__((ext_vector_type(4)));
typedef unsigned short us8v __attribute__((ext_vector_type(8)));

#define NTOK 65536   // B*S = 8*8192 tokens
#define DMODEL 512

// round-to-nearest-even f32 -> bf16 bits
__device__ __forceinline__ unsigned short f2bf(float f) {
  unsigned int u = __float_as_uint(f);
  u += 0x7fffu + ((u >> 16) & 1u);
  return (unsigned short)(u >> 16);
}

// fast tanh-GELU: x * u/(u+1), u = exp(2*0.7978845608*(x + 0.044715 x^3))
__device__ __forceinline__ float gelu_fast(float x) {
  float x3 = x * x * x;
  float u = __expf(1.5957691216057308f * (x + 0.044715f * x3));
  return x * __fdividef(u, u + 1.0f);
}

// async global->LDS, 16B per lane; LDS dest is wave-uniform base (+lane*16 by HW)
__device__ __forceinline__ void async16(const void* g, void* l) {
  __builtin_amdgcn_global_load_lds((const __attribute__((address_space(1))) void*)g,
                                   (__attribute__((address_space(3))) void*)l,
                                   16, 0, 0);
}

// ---------- fp32 -> bf16 weight conversion ----------
__global__ __launch_bounds__(256) void cvt_bf16_kernel(const float4* __restrict__ in,
                                                       us4v* __restrict__ out, int n4) {
  int i = blockIdx.x * 256 + threadIdx.x;
  if (i < n4) {
    float4 v = in[i];
    us4v o;
    o.x = f2bf(v.x); o.y = f2bf(v.y); o.z = f2bf(v.z); o.w = f2bf(v.w);
    out[i] = o;
  }
}

// ---------- LayerNorm: one wave per 512-float row, bf16 output ----------
__global__ __launch_bounds__(256) void ln_kernel(const float* __restrict__ x,
                                                 const float* __restrict__ g,
                                                 const float* __restrict__ b,
                                                 unsigned short* __restrict__ out) {
  const int w = threadIdx.x >> 6;
  const int lane = threadIdx.x & 63;
  const size_t row = (size_t)blockIdx.x * 4 + w;
  const float4* xv = (const float4*)(x + row * DMODEL);
  float4 v0 = xv[lane * 2];
  float4 v1 = xv[lane * 2 + 1];
  float s  = v0.x + v0.y + v0.z + v0.w + v1.x + v1.y + v1.z + v1.w;
  float ss = v0.x*v0.x + v0.y*v0.y + v0.z*v0.z + v0.w*v0.w
           + v1.x*v1.x + v1.y*v1.y + v1.z*v1.z + v1.w*v1.w;
#pragma unroll
  for (int m = 1; m < 64; m <<= 1) {
    s  += __shfl_xor(s, m, 64);
    ss += __shfl_xor(ss, m, 64);
  }
  const float mean = s * (1.0f / DMODEL);
  const float var  = ss * (1.0f / DMODEL) - mean * mean;
  const float rstd = rsqrtf(var + 1e-5f);
  const int c = lane * 8;
  const float4* gv = (const float4*)(g + c);
  const float4* bv = (const float4*)(b + c);
  float4 g0 = gv[0], g1 = gv[1], bb0 = bv[0], bb1 = bv[1];
  us8v o;
  o[0] = f2bf((v0.x - mean) * rstd * g0.x + bb0.x);
  o[1] = f2bf((v0.y - mean) * rstd * g0.y + bb0.y);
  o[2] = f2bf((v0.z - mean) * rstd * g0.z + bb0.z);
  o[3] = f2bf((v0.w - mean) * rstd * g0.w + bb0.w);
  o[4] = f2bf((v1.x - mean) * rstd * g1.x + bb1.x);
  o[5] = f2bf((v1.y - mean) * rstd * g1.y + bb1.y);
  o[6] = f2bf((v1.z - mean) * rstd * g1.z + bb1.z);
  o[7] = f2bf((v1.w - mean) * rstd * g1.w + bb1.w);
  *(us8v*)(out + row * DMODEL + c) = o;
}

// ---------- bf16 GEMM, 256x256 tile, 8-phase counted-vmcnt schedule ----------
// C[M,N] = A[M,K] @ B[N,K]^T (+bias)(+resid)(+gelu)
// 512 threads = 8 waves (2m x 4n), per-wave 128x64 output, acc[8][4] f32x4.
// BK=64, 2 LDS buffers (A 32K + B 32K each) = 128 KiB, 1 block/CU.
// Per K-tile, 4 phases of 16 MFMA each:
//   P1: ds_read A[m0-3]x2s + B[n0-1]x2s (12)          | barrier, lgkm0, MFMA q(0,0)
//   P2: ds_read A[m4-7]x2s + B[n2-3]x2s (12)          | barrier, lgkm0, MFMA q(0,1)
//        -> after P2-end barrier ALL reads of buf[t&1] are retired (lgkm0 before
//           each wave's P2 MFMA), so buf[t&1] is free for restaging.
//   P3: issue 4x global_load_lds (A of tile t+2 -> buf[t&1]) | barrier, MFMA q(1,0)
//   P4: issue 4x global_load_lds (B of tile t+2)             | barrier, MFMA q(1,1)
//   end of tile: s_waitcnt vmcnt(8)  (allows t+2's 8 loads in flight, forces
//   t+1's loads complete) + s_barrier. vmcnt(0) only at t==NT-2 (tail drain).
// Raw s_barrier throughout: no __syncthreads -> no implicit vmcnt(0) drain.
// LDS layout: my verified XOR-unit swizzle (16B unit (r,kg) at r*8 + (kg^(r&7)));
// bank-conflict-free (measured 0.0) and the pre-swizzled global source keeps
// global_load_lds dests linear (both-sides-or-neither rule).
// XCD band scheduling retained (block n -> XCD n%8; bands sized for L2).
#define MFMA_Q(mh, nh)                                                           \
  {                                                                              \
    _Pragma("unroll") for (int s = 0; s < 2; ++s)                                \
        _Pragma("unroll") for (int mi = 0; mi < 4; ++mi)                         \
            _Pragma("unroll") for (int ni = 0; ni < 2; ++ni)                     \
                acc[(mh) * 4 + mi][(nh) * 2 + ni] =                              \
        __builtin_amdgcn_mfma_f32_16x16x32_bf16(af[s][(mh) * 4 + mi],            \
                                                bfr[s][(nh) * 2 + ni],           \
                                                acc[(mh) * 4 + mi][(nh) * 2 + ni],\
                                                0, 0, 0);                        \
  }

template <int EPI, bool EXPERT, typename OutT, int K>
__global__ __launch_bounds__(512, 2) void gemm8p(
    const unsigned short* __restrict__ A, const unsigned short* __restrict__ B,
    const float* __restrict__ bias, const float* __restrict__ resid,
    OutT* __restrict__ C, int N) {
  __shared__ alignas(16) unsigned short lds[2][2][16384];  // [buf][A/B][256*64]
  const int tid = threadIdx.x;
  const int w = tid >> 6;
  const int lane = tid & 63;
  const int wm = w >> 2, wn = w & 3;        // 2 x 4 wave grid
  const int quad = lane >> 4, lm = lane & 15;

  // ---- XCD-aware band block swizzle ----
  const int ncol = N >> 8;                  // 2 or 8 column tiles
  const int perx = gridDim.x >> 3;          // grid % 8 == 0
  const int xcd = blockIdx.x & 7;
  const int wk = xcd * perx + (blockIdx.x >> 3);
  // band A-slab ~<=2 MB: rows_tiles <= 4096/K (and 4 for the wide-N fc1 case)
  const int band_rows = (K == 2048) ? 2 : (ncol >= 8 ? 4 : 8);
  const int bb = band_rows * ncol;
  const int band = wk / bb;
  const int rem = wk - band * bb;
  const int ct = rem / band_rows;
  const int rib = rem - ct * band_rows;
  const size_t row0 = (size_t)(band * band_rows + rib) * 256;
  const int col0 = ct * 256;

  const unsigned short* Bp = B;
  const float* biasp = bias;
  if (EXPERT) {
    const int e = (int)((row0 >> 12) & 7);  // (token/4096) % 8, tiles expert-aligned
    Bp += (size_t)e * (size_t)N * (size_t)K;
    biasp += (size_t)e * (size_t)N;
  }

  // ---- staging addresses ----
  // Per tile: A = 32 chunks of 1 KiB (64 16B-units), wave w owns chunks w*4+j.
  // chunk c, lane l -> phys unit f = c*64 + l; r = f>>3, u = f&7, kg = u^(r&7)
  // (r&7 = (lane>>3), independent of c). Source for chunk j = base + j*8 rows.
  const int r0 = w * 32 + (lane >> 3);
  const int kg0 = (lane & 7) ^ (lane >> 3);
  const unsigned short* gA = A + (row0 + (size_t)r0) * (size_t)K + kg0 * 8;
  const unsigned short* gB = Bp + ((size_t)col0 + (size_t)r0) * (size_t)K + kg0 * 8;

  auto stageA = [&](int buf, const unsigned short* p) {
    unsigned short* l = &lds[buf][0][(w * 4) * 512];
    async16(p, l);
    async16(p + 8 * K, l + 512);
    async16(p + 16 * K, l + 1024);
    async16(p + 24 * K, l + 1536);
  };
  auto stageB = [&](int buf, const unsigned short* p) {
    unsigned short* l = &lds[buf][1][(w * 4) * 512];
    async16(p, l);
    async16(p + 8 * K, l + 512);
    async16(p + 16 * K, l + 1024);
    async16(p + 24 * K, l + 1536);
  };

  f32x4 acc[8][4] = {};
  const int NT = K / 64;

  // ---- prologue: stage tiles 0 and 1 ----
  stageA(0, gA);
  stageB(0, gB);
  stageA(1, gA + 64);
  stageB(1, gB + 64);
  gA += 128;   // now points at tile-2 source
  gB += 128;
  asm volatile("s_waitcnt vmcnt(8)" ::: "memory");  // tile 0 landed, tile 1 in flight
  __builtin_amdgcn_s_barrier();

  for (int t = 0; t < NT; ++t) {
    const unsigned short* tA = &lds[t & 1][0][0];
    const unsigned short* tB = &lds[t & 1][1][0];
    const bool st = (t + 2 < NT);
    bf16x8 af[2][8], bfr[2][4];

    // ---- P1: reads A[m0-3], B[n0-1] ----
#pragma unroll
    for (int s = 0; s < 2; ++s) {
#pragma unroll
      for (int mi = 0; mi < 4; ++mi) {
        const int r = wm * 128 + mi * 16 + lm;
        af[s][mi] = *(const bf16x8*)&tA[(r * 8 + ((s * 4 + quad) ^ (r & 7))) * 8];
      }
#pragma unroll
      for (int ni = 0; ni < 2; ++ni) {
        const int c = wn * 64 + ni * 16 + lm;
        bfr[s][ni] = *(const bf16x8*)&tB[(c * 8 + ((s * 4 + quad) ^ (c & 7))) * 8];
      }
    }
    __builtin_amdgcn_s_barrier();
    asm volatile("s_waitcnt lgkmcnt(0)" ::: "memory");
    __builtin_amdgcn_s_setprio(1);
    MFMA_Q(0, 0);
    __builtin_amdgcn_s_setprio(0);
    __builtin_amdgcn_s_barrier();

    // ---- P2: reads A[m4-7], B[n2-3] ----
#pragma unroll
    for (int s = 0; s < 2; ++s) {
#pragma unroll
      for (int mi = 0; mi < 4; ++mi) {
        const int r = wm * 128 + (mi + 4) * 16 + lm;
        af[s][mi + 4] = *(const bf16x8*)&tA[(r * 8 + ((s * 4 + quad) ^ (r & 7))) * 8];
      }
#pragma unroll
      for (int ni = 0; ni < 2; ++ni) {
        const int c = wn * 64 + (ni + 2) * 16 + lm;
        bfr[s][ni + 2] = *(const bf16x8*)&tB[(c * 8 + ((s * 4 + quad) ^ (c & 7))) * 8];
      }
    }
    __builtin_amdgcn_s_barrier();
    asm volatile("s_waitcnt lgkmcnt(0)" ::: "memory");
    __builtin_amdgcn_s_setprio(1);
    MFMA_Q(0, 1);
    __builtin_amdgcn_s_setprio(0);
    __builtin_amdgcn_s_barrier();
    // all reads of buf[t&1] retired by every wave -> safe to restage it

    // ---- P3: stage A of tile t+2 into buf[t&1] ----
    if (st) stageA(t & 1, gA);
    __builtin_amdgcn_s_barrier();
    __builtin_amdgcn_s_setprio(1);
    MFMA_Q(1, 0);
    __builtin_amdgcn_s_setprio(0);
    __builtin_amdgcn_s_barrier();

    // ---- P4: stage B of tile t+2 ----
    if (st) {
      stageB(t & 1, gB);
      gA += 64;
      gB += 64;
    }
    __builtin_amdgcn_s_barrier();
    __builtin_amdgcn_s_setprio(1);
    MFMA_Q(1, 1);
    __builtin_amdgcn_s_setprio(0);

    // ---- tile-end wait: make tile t+1 ready; keep t+2's 8 loads in flight ----
    if (t < NT - 2) {
      asm volatile("s_waitcnt vmcnt(8)" ::: "memory");
      __builtin_amdgcn_s_barrier();
    } else if (t == NT - 2) {
      asm volatile("s_waitcnt vmcnt(0)" ::: "memory");
      __builtin_amdgcn_s_barrier();
    }
    // t == NT-1: fall through to epilogue (no LDS use there)
  }

  // ---- epilogue: C/D layout col=lane&15, row=quad*4+r ----
#pragma unroll
  for (int mi = 0; mi < 8; ++mi) {
#pragma unroll
    for (int ni = 0; ni < 4; ++ni) {
      const int col = col0 + wn * 64 + ni * 16 + lm;
      const float bv = biasp[col];
#pragma unroll
      for (int r = 0; r < 4; ++r) {
        const size_t grow = row0 + (size_t)(wm * 128 + mi * 16 + quad * 4 + r);
        float v = acc[mi][ni][r] + bv;
        if constexpr (EPI == 0) v += resid[grow * (size_t)N + col];
        if constexpr (EPI == 1) v = gelu_fast(v);
        if constexpr (sizeof(OutT) == 4) {
          C[grow * (size_t)N + col] = v;
        } else {
          C[grow * (size_t)N + col] = (OutT)f2bf(v);
        }
      }
    }
  }
}

// ---------- launch ----------
extern "C" void kernel_launch(void* const* d_in, const int* in_sizes, int n_in,
                              void* d_out, int out_size, void* d_ws, size_t ws_size,
                              hipStream_t stream) {
  const float* x      = (const float*)d_in[0];
  const float* ln_g   = (const float*)d_in[1];
  const float* ln_b   = (const float*)d_in[2];
  const float* attn_w = (const float*)d_in[3];
  const float* attn_b = (const float*)d_in[4];
  // d_in[5] = gate_w : logits/top-k are dead code for the output -> skipped
  const float* fc1_w  = (const float*)d_in[6];
  const float* fc1_b  = (const float*)d_in[7];
  const float* fc2_w  = (const float*)d_in[8];
  const float* fc2_b  = (const float*)d_in[9];
  const float* next_w = (const float*)d_in[10];
  const float* next_b = (const float*)d_in[11];

  char* ws = (char*)d_ws;
  const size_t MB = 1024ull * 1024ull;
  unsigned short* wN    = (unsigned short*)(ws);             // 64 MiB: normed, later y
  unsigned short* wXat  = (unsigned short*)(ws + 64 * MB);   // 64 MiB: x_attn (bf16)
  unsigned short* wH    = (unsigned short*)(ws + 128 * MB);  // 256 MiB: gelu(h) (bf16)
  unsigned short* attnbf = (unsigned short*)(ws + 384 * MB); // 0.5 MiB
  unsigned short* fc1bf  = (unsigned short*)(ws + 385 * MB); // 16 MiB
  unsigned short* fc2bf  = (unsigned short*)(ws + 401 * MB); // 16 MiB
  unsigned short* nextbf = (unsigned short*)(ws + 417 * MB); // 0.5 MiB

  // weights fp32 -> bf16 (cheap: ~17.3M elements)
  {
    int n4;
    n4 = (512 * 512) / 4;
    cvt_bf16_kernel<<<dim3((n4 + 255) / 256), dim3(256), 0, stream>>>((const float4*)attn_w, (us4v*)attnbf, n4);
    n4 = (8 * 2048 * 512) / 4;
    cvt_bf16_kernel<<<dim3((n4 + 255) / 256), dim3(256), 0, stream>>>((const float4*)fc1_w, (us4v*)fc1bf, n4);
    n4 = (8 * 512 * 2048) / 4;
    cvt_bf16_kernel<<<dim3((n4 + 255) / 256), dim3(256), 0, stream>>>((const float4*)fc2_w, (us4v*)fc2bf, n4);
    n4 = (512 * 512) / 4;
    cvt_bf16_kernel<<<dim3((n4 + 255) / 256), dim3(256), 0, stream>>>((const float4*)next_w, (us4v*)nextbf, n4);
  }

  // LayerNorm -> wN (bf16 normed)
  ln_kernel<<<dim3(NTOK / 4), dim3(256), 0, stream>>>(x, ln_g, ln_b, wN);

  // x_attn = normed @ attn_w^T + attn_b + x   -> wXat (bf16)
  gemm8p<0, false, unsigned short, 512><<<dim3((NTOK / 256) * 2), dim3(512), 0, stream>>>(
      wN, attnbf, attn_b, x, wXat, 512);

  // h = gelu(x_attn @ fc1_w[e]^T + fc1_b[e])  -> wH (bf16)
  gemm8p<1, true, unsigned short, 512><<<dim3((NTOK / 256) * 8), dim3(512), 0, stream>>>(
      wXat, fc1bf, fc1_b, nullptr, wH, 2048);

  // y = h @ fc2_w[e]^T + fc2_b[e]             -> wN (bf16, reuse)
  gemm8p<2, true, unsigned short, 2048><<<dim3((NTOK / 256) * 2), dim3(512), 0, stream>>>(
      wH, fc2bf, fc2_b, nullptr, wN, 512);

  // out = gelu(y @ next_w^T + next_b)         -> d_out (fp32)
  gemm8p<1, false, float, 512><<<dim3((NTOK / 256) * 2), dim3(512), 0, stream>>>(
      wN, nextbf, next_b, nullptr, (float*)d_out, 512);
}